// Round 1
// 282.731 us; speedup vs baseline: 1.1157x; 1.1157x over previous
//
#include <hip/hip_runtime.h>

#define IN_NODE 128
#define OUT_NODE 64
#define NHEAD 4
#define HN 256                 // NHEAD * OUT_NODE
#define HE 64                  // NHEAD * OUT_EDGE
#define LEAKY 0.01f
#define MAXD 96                // cached slots per wave in fused aggregate

typedef __attribute__((ext_vector_type(8))) short bf16x8;
typedef __attribute__((ext_vector_type(4))) float f32x4;

__device__ __forceinline__ float bf2f(unsigned short u) {
    union { unsigned u; float f; } v; v.u = ((unsigned)u) << 16; return v.f;
}
__device__ __forceinline__ unsigned short f2bf(float x) {
    union { float f; unsigned u; } v; v.f = x;
    unsigned r = v.u + 0x7FFF + ((v.u >> 16) & 1);   // RNE
    return (unsigned short)(r >> 16);
}
__device__ __forceinline__ bf16x8 cvt8(float4 a, float4 b) {
    bf16x8 r;
    r[0] = (short)f2bf(a.x); r[1] = (short)f2bf(a.y);
    r[2] = (short)f2bf(a.z); r[3] = (short)f2bf(a.w);
    r[4] = (short)f2bf(b.x); r[5] = (short)f2bf(b.y);
    r[6] = (short)f2bf(b.z); r[7] = (short)f2bf(b.w);
    return r;
}

// ------ prep: wsum (block 0) + W -> fragment-contiguous bf16 WB (blocks 1..12)
//        + degree histogram (blocks 13..)
// WB layout: 24 groups (0..3 = W_ni cols 0..63; 4..19 = W_ns cols 0..255;
//            20..23 = W_nj cols 0..63). Per group: 4 K-chunks x 64 lanes x 8
//            bf16, where lane l holds W[k = c*32 + (l>>4)*8 + j][col = g16 + (l&15)].
//            One GEMM B-load = 1 KB fully coalesced.
__global__ void prep_hist(const float* __restrict__ W_fij,
                          const float* __restrict__ W_ni,
                          const float* __restrict__ W_ns,
                          const float* __restrict__ W_nj,
                          const int* __restrict__ dst,
                          float* __restrict__ wsum, unsigned short* __restrict__ WT,
                          int* __restrict__ cnt, int E) {
    int b = blockIdx.x;
    if (b == 0) {
        int k = threadIdx.x;
        if (k < 64) {
            float s = 0.f;
#pragma unroll
            for (int c = 0; c < 16; ++c) s += W_fij[c * 64 + k];
            wsum[k] = s;
        }
        return;
    }
    if (b <= 12) {
        int base = (b - 1) * 4096 + threadIdx.x;
#pragma unroll
        for (int i = 0; i < 16; ++i) {
            int idx = base + i * 256;
            int g   = idx >> 11;          // group (24)
            int rem = idx & 2047;
            int c   = rem >> 9;           // K-chunk (4)
            int l   = (rem >> 3) & 63;    // lane
            int j   = rem & 7;            // element within fragment
            int nl  = l & 15;
            int k   = c * 32 + (l >> 4) * 8 + j;
            unsigned short v;
            if (g < 4)       v = f2bf(W_ni[k * 64  + g * 16 + nl]);
            else if (g < 20) v = f2bf(W_ns[k * 256 + (g - 4) * 16 + nl]);
            else             v = f2bf(W_nj[k * 64  + (g - 20) * 16 + nl]);
            WT[idx] = v;
        }
        return;
    }
    int i = (b - 13) * 256 + threadIdx.x;
    if (i < E) atomicAdd(&cnt[dst[i]], 1);
}

// ------- scan_all: full exclusive scan of cnt -> row_ptr, one dispatch ------
__global__ __launch_bounds__(256) void scan_all(const int* __restrict__ cnt,
                                                int* __restrict__ row_ptr,
                                                int* __restrict__ partials,
                                                int* __restrict__ flags,
                                                int n, int E, int nb) {
    __shared__ int sums[256];
    __shared__ int s_base;
    int tid = threadIdx.x, b = blockIdx.x;
    int base = b * 1024;
    int v[4]; int tsum = 0;
#pragma unroll
    for (int j = 0; j < 4; ++j) {
        int idx = base + tid * 4 + j;
        v[j] = (idx < n) ? cnt[idx] : 0;
        tsum += v[j];
    }
    sums[tid] = tsum;
    __syncthreads();
    for (int off = 1; off < 256; off <<= 1) {
        int x = (tid >= off) ? sums[tid - off] : 0;
        __syncthreads();
        sums[tid] += x;
        __syncthreads();
    }
    if (tid == 255) {
        __hip_atomic_store(&partials[b], sums[255], __ATOMIC_RELAXED, __HIP_MEMORY_SCOPE_AGENT);
        __hip_atomic_store(&flags[b], 1, __ATOMIC_RELEASE, __HIP_MEMORY_SCOPE_AGENT);
    }
    if (tid < 64) {
        int val = 0;
        if (tid < nb) {
            while (__hip_atomic_load(&flags[tid], __ATOMIC_ACQUIRE, __HIP_MEMORY_SCOPE_AGENT) == 0) {
                __builtin_amdgcn_s_sleep(1);
            }
            val = __hip_atomic_load(&partials[tid], __ATOMIC_RELAXED, __HIP_MEMORY_SCOPE_AGENT);
        }
#pragma unroll
        for (int o = 1; o < 64; o <<= 1) {
            int x = __shfl_up(val, o);
            if (tid >= o) val += x;
        }
        int off = (b > 0) ? __shfl(val, b - 1) : 0;
        if (tid == 0) s_base = off;
    }
    __syncthreads();
    int run = s_base + sums[tid] - tsum;   // global exclusive prefix
#pragma unroll
    for (int j = 0; j < 4; ++j) {
        int idx = base + tid * 4 + j;
        if (idx < n) row_ptr[idx] = run;
        run += v[j];
    }
    if (b == nb - 1 && tid == 0) row_ptr[n] = E;
}

// ---- GEMM tile: 64 rows of A x (NG*16) output cols, A staged in LDS once ---
// LDS: 64 x 128 bf16, stored in 16B granules, byte-offset XOR-swizzled with
// (row&7)<<4 so per-lane fragment ds_read_b128 is bank-uniform.
template<int NG, int G0>
__device__ __forceinline__ void gemm_tile(
    const float* __restrict__ A, int rowBase, int M,
    const unsigned short* __restrict__ WB, const float* __restrict__ b_ns,
    unsigned short* __restrict__ f_ni, unsigned short* __restrict__ h_src,
    unsigned short* __restrict__ f_nj, unsigned short* As)
{
    const int t = threadIdx.x;
    const float4* A4 = reinterpret_cast<const float4*>(A);
    // ---- stage A tile (coalesced: 2 loads @ 32B stride cover 2KB/instr-pair)
#pragma unroll
    for (int j = 0; j < 4; ++j) {
        int gi = j * 256 + t;            // granule index (8 floats)
        int r  = gi >> 4;                // tile row (0..63)
        int gr = rowBase + r; if (gr >= M) gr = M - 1;   // clamp, stores guarded
        int fi = (gi & 15) * 2;          // float4 index within row
        float4 a0 = A4[(size_t)gr * 32 + fi];
        float4 a1 = A4[(size_t)gr * 32 + fi + 1];
        int byteoff = (gi * 16) ^ ((r & 7) << 4);
        *reinterpret_cast<bf16x8*>(reinterpret_cast<char*>(As) + byteoff) = cvt8(a0, a1);
    }
    __syncthreads();

    const int lane = t & 63, w = t >> 6;
    const int rw = rowBase + w * 16;
    if (rw >= M) return;                 // tail wave, nothing to compute
    const int m = lane & 15, q = lane >> 4;
    const int tr = w * 16 + m;

    f32x4 acc[NG] = {};
    const char* Asb = reinterpret_cast<const char*>(As);
#pragma unroll
    for (int c = 0; c < 4; ++c) {
        int gi  = tr * 16 + c * 4 + q;
        int off = (gi * 16) ^ ((tr & 7) << 4);
        bf16x8 af = *reinterpret_cast<const bf16x8*>(Asb + off);
#pragma unroll
        for (int g = 0; g < NG; ++g) {
            bf16x8 bf = *reinterpret_cast<const bf16x8*>(
                WB + (size_t)(((G0 + g) * 4 + c) * 64 + lane) * 8);
            acc[g] = __builtin_amdgcn_mfma_f32_16x16x32_bf16(af, bf, acc[g], 0, 0, 0);
        }
    }

#pragma unroll
    for (int g = 0; g < NG; ++g) {
        const int ga = G0 + g;
        unsigned short* C; int N, colBase; const float* bias = nullptr;
        if (ga < 4)       { C = f_ni;  N = 64;  colBase = ga * 16; }
        else if (ga < 20) { C = h_src; N = 256; colBase = (ga - 4) * 16; bias = b_ns; }
        else              { C = f_nj;  N = 64;  colBase = (ga - 20) * 16; }
        int col = colBase + m;
        float bv = bias ? bias[col] : 0.f;
#pragma unroll
        for (int rr = 0; rr < 4; ++rr) {
            int orow = rw + q * 4 + rr;
            if (orow < M) C[(size_t)orow * N + col] = f2bf(acc[g][rr] + bv);
        }
    }
}

// ---------------- mega: gemm + scatter, STRIPED roles (1:2 per 3) -----------
__global__ __launch_bounds__(256) void mega(
    const float* __restrict__ nfeats, const float* __restrict__ dst_feats,
    const unsigned short* __restrict__ WT, const float* __restrict__ b_ns,
    const int* __restrict__ src, const int* __restrict__ dst,
    const float* __restrict__ reward, const int* __restrict__ row_ptr,
    int* __restrict__ cnt,
    unsigned short* __restrict__ f_ni, unsigned short* __restrict__ h_src,
    unsigned short* __restrict__ f_nj, int2* __restrict__ sr_s,
    int Ns, int Nd, int E, int nBlkNf, int nBlkDj, int nScatter)
{
    __shared__ __align__(16) unsigned short As[64 * 128];
    const int g = blockIdx.x / 3, r = blockIdx.x % 3;
    if (r == 0) {                               // ---- GEMM role ----
        if (g < nBlkNf) {
            // nfeats tile: f_ni (64 cols) + h_src (256 cols), A read ONCE
            gemm_tile<20, 0>(nfeats, g * 64, Ns, WT, b_ns, f_ni, h_src, f_nj, As);
        } else if (g < nBlkNf + nBlkDj) {
            gemm_tile<4, 20>(dst_feats, (g - nBlkNf) * 64, Nd, WT, b_ns, f_ni, h_src, f_nj, As);
        }
        return;
    }
    // ---- scatter role ----
    const int sb = g * 2 + (r - 1);
    if (sb >= nScatter) return;
    int i = sb * 256 + threadIdx.x;
    if (i >= E) return;
    int d = dst[i];
    int pos = row_ptr[d] + atomicSub(&cnt[d], 1) - 1;
    sr_s[pos] = make_int2(src[i], __float_as_int(reward[i]));
}

// ------- fused logits + softmax + aggregation (unchanged) -------------------
__global__ __launch_bounds__(256) void fused_agg(
    const unsigned short* __restrict__ f_ni, const unsigned short* __restrict__ f_nj,
    const unsigned short* __restrict__ h_src, const int2* __restrict__ sr_s,
    const int* __restrict__ row_ptr,
    const float* __restrict__ wsum, const float* __restrict__ b_e,
    const float* __restrict__ attn, float* __restrict__ out, int Nd)
{
    __shared__ float s_e[4][MAXD][4];
    __shared__ int   s_sn[4][MAXD];
    const int wv = threadIdx.x >> 6, lane = threadIdx.x & 63;
    const int d = blockIdx.x * 4 + wv;
    if (d >= Nd) return;
    const int l = lane & 15, sub = lane >> 4;
    const int beg = row_ptr[d];
    const int end = row_ptr[d + 1];

    for (int i = lane; i < MAXD; i += 64) s_sn[wv][i] = -1;  // sentinel pad

    ushort4 uj = *reinterpret_cast<const ushort4*>(f_nj + (size_t)d * HE + 4 * l);
    float4 fnj = { bf2f(uj.x), bf2f(uj.y), bf2f(uj.z), bf2f(uj.w) };
    float4 ws = *reinterpret_cast<const float4*>(wsum + 4 * l);
    float4 be = *reinterpret_cast<const float4*>(b_e + 4 * l);
    float4 at = *reinterpret_cast<const float4*>(attn + 4 * l);

    float den = 0.f;
    for (int base = beg; base < end; base += 4) {
        int slot = base + sub;
        if (slot < end) {
            int2 sr = sr_s[slot];
            int sn = sr.x;
            float r = __int_as_float(sr.y);
            ushort4 ui = *reinterpret_cast<const ushort4*>(f_ni + (size_t)sn * HE + 4 * l);
            float t, v;
            v = bf2f(ui.x) + fnj.x + r * ws.x + be.x; v = (v >= 0.f) ? v : LEAKY * v; t  = v * at.x;
            v = bf2f(ui.y) + fnj.y + r * ws.y + be.y; v = (v >= 0.f) ? v : LEAKY * v; t += v * at.y;
            v = bf2f(ui.z) + fnj.z + r * ws.z + be.z; v = (v >= 0.f) ? v : LEAKY * v; t += v * at.z;
            v = bf2f(ui.w) + fnj.w + r * ws.w + be.w; v = (v >= 0.f) ? v : LEAKY * v; t += v * at.w;
            t += __shfl_xor(t, 1);
            t += __shfl_xor(t, 2);          // lanes 4h..4h+3 of subgroup hold head h logit
            float ev = __expf(t);
            den += ev;
            int idx = slot - beg;
            if (idx < MAXD) {
                if ((l & 3) == 0) s_e[wv][idx][l >> 2] = ev;
                if (l == 0) s_sn[wv][idx] = sn;
            }
        }
    }
    den += __shfl_xor(den, 16);
    den += __shfl_xor(den, 32);             // total for head (l>>2), all subgroups
    float dh = __shfl(den, (lane >> 4) << 2);   // head lane>>4's denominator
    float invh = (dh > 0.f) ? 1.f / dh : 0.f;
    const int h = lane >> 4;

    float a0 = 0.f, a1 = 0.f, a2 = 0.f, a3 = 0.f;
    int cap = min(end - beg, MAXD);
    int npad = (cap + 7) & ~7;
    for (int idx0 = 0; idx0 < npad; idx0 += 8) {
#pragma unroll
        for (int j = 0; j < 8; ++j) {
            int idx = idx0 + j;
            int sn = s_sn[wv][idx];
            float wgt = (sn >= 0) ? s_e[wv][idx][h] * invh : 0.f;
            int sa = (sn >= 0) ? sn : 0;
            ushort4 u = *reinterpret_cast<const ushort4*>(h_src + (size_t)sa * HN + lane * 4);
            a0 = fmaf(wgt, bf2f(u.x), a0);
            a1 = fmaf(wgt, bf2f(u.y), a1);
            a2 = fmaf(wgt, bf2f(u.z), a2);
            a3 = fmaf(wgt, bf2f(u.w), a3);
        }
    }
    // overflow tail (degree > MAXD): recompute logits serially (cold path)
    for (int slot = beg + MAXD; slot < end; ++slot) {
        int2 sr = sr_s[slot];
        int sn = sr.x;
        float r = __int_as_float(sr.y);
        float v = bf2f(f_ni[(size_t)sn * HE + lane]) + bf2f(f_nj[(size_t)d * HE + lane])
                + r * wsum[lane] + b_e[lane];
        v = (v >= 0.f) ? v : LEAKY * v;
        float t = v * attn[lane];
        t += __shfl_xor(t, 1);
        t += __shfl_xor(t, 2);
        t += __shfl_xor(t, 4);
        t += __shfl_xor(t, 8);
        float wgt = __expf(t) * invh;
        ushort4 u = *reinterpret_cast<const ushort4*>(h_src + (size_t)sn * HN + lane * 4);
        a0 = fmaf(wgt, bf2f(u.x), a0);
        a1 = fmaf(wgt, bf2f(u.y), a1);
        a2 = fmaf(wgt, bf2f(u.z), a2);
        a3 = fmaf(wgt, bf2f(u.w), a3);
    }

    a0 += __shfl_xor(a0, 16); a0 += __shfl_xor(a0, 32);
    a1 += __shfl_xor(a1, 16); a1 += __shfl_xor(a1, 32);
    a2 += __shfl_xor(a2, 16); a2 += __shfl_xor(a2, 32);
    a3 += __shfl_xor(a3, 16); a3 += __shfl_xor(a3, 32);
    if (lane < 16) {
        float4 o = { fmaxf(a0 * 0.25f, 0.f), fmaxf(a1 * 0.25f, 0.f),
                     fmaxf(a2 * 0.25f, 0.f), fmaxf(a3 * 0.25f, 0.f) };
        *reinterpret_cast<float4*>(out + (size_t)d * OUT_NODE + lane * 4) = o;
    }
}

static inline char* align256(char* p) {
    return (char*)(((uintptr_t)p + 255) & ~(uintptr_t)255);
}

extern "C" void kernel_launch(void* const* d_in, const int* in_sizes, int n_in,
                              void* d_out, int out_size, void* d_ws, size_t ws_size,
                              hipStream_t stream) {
    const float* nfeats    = (const float*)d_in[0];
    const float* dst_feats = (const float*)d_in[1];
    const float* reward    = (const float*)d_in[2];
    const int*   src       = (const int*)d_in[3];
    const int*   dst       = (const int*)d_in[4];
    const float* W_ns      = (const float*)d_in[5];
    const float* b_ns      = (const float*)d_in[6];
    const float* W_ni      = (const float*)d_in[7];
    const float* W_nj      = (const float*)d_in[8];
    const float* W_fij     = (const float*)d_in[9];
    const float* attn      = (const float*)d_in[10];
    const float* b_e       = (const float*)d_in[11];
    float* out = (float*)d_out;

    const int Ns = in_sizes[0] / IN_NODE;
    const int Nd = in_sizes[1] / IN_NODE;
    const int E  = in_sizes[2];

    char* ws = (char*)d_ws;
    unsigned short* f_ni  = (unsigned short*)ws; ws = align256(ws + (size_t)Ns * HE * 2);
    unsigned short* f_nj  = (unsigned short*)ws; ws = align256(ws + (size_t)Nd * HE * 2);
    unsigned short* h_src = (unsigned short*)ws; ws = align256(ws + (size_t)Ns * HN * 2);
    unsigned short* WT    = (unsigned short*)ws; ws = align256(ws + 49152 * 2);
    float* wsum    = (float*)ws; ws = align256(ws + HE * 4);
    int*   cnt     = (int*)ws;   // cnt + flags zeroed by one memset
    int*   flags   = cnt + Nd;   ws = align256(ws + (size_t)(Nd + 64) * 4);
    int*   row_ptr = (int*)ws;   ws = align256(ws + (size_t)(Nd + 1) * 4);
    int*   partials= (int*)ws;   ws = align256(ws + 256 * 4);
    int2*  sr_s    = (int2*)ws;  ws = align256(ws + (size_t)E * 8);

    hipMemsetAsync(cnt, 0, (size_t)(Nd + 64) * 4, stream);

    prep_hist<<<13 + (E + 255) / 256, 256, 0, stream>>>(
        W_fij, W_ni, W_ns, W_nj, dst, wsum, WT, cnt, E);

    int nb = (Nd + 1023) / 1024;
    scan_all<<<nb, 256, 0, stream>>>(cnt, row_ptr, partials, flags, Nd, E, nb);

    int nBlkNf = (Ns + 63) / 64;
    int nBlkDj = (Nd + 63) / 64;
    int nG = nBlkNf + nBlkDj;
    int nScatter = (E + 255) / 256;
    int nGroups = (nG > (nScatter + 1) / 2) ? nG : (nScatter + 1) / 2;
    mega<<<nGroups * 3, 256, 0, stream>>>(
        nfeats, dst_feats, WT, b_ns, src, dst, reward, row_ptr, cnt,
        f_ni, h_src, f_nj, sr_s, Ns, Nd, E, nBlkNf, nBlkDj, nScatter);

    fused_agg<<<(Nd + 3) / 4, 256, 0, stream>>>(
        f_ni, f_nj, h_src, sr_s, row_ptr, wsum, b_e, attn, out, Nd);
}

// Round 2
// 278.070 us; speedup vs baseline: 1.1344x; 1.0168x over previous
//
#include <hip/hip_runtime.h>

#define IN_NODE 128
#define OUT_NODE 64
#define NHEAD 4
#define HN 256                 // NHEAD * OUT_NODE
#define HE 64                  // NHEAD * OUT_EDGE
#define LEAKY 0.01f

typedef __attribute__((ext_vector_type(8))) short bf16x8;
typedef __attribute__((ext_vector_type(4))) float f32x4;

__device__ __forceinline__ float bf2f(unsigned short u) {
    union { unsigned u; float f; } v; v.u = ((unsigned)u) << 16; return v.f;
}
__device__ __forceinline__ unsigned short f2bf(float x) {
    union { float f; unsigned u; } v; v.f = x;
    unsigned r = v.u + 0x7FFF + ((v.u >> 16) & 1);   // RNE
    return (unsigned short)(r >> 16);
}
__device__ __forceinline__ bf16x8 cvt8(float4 a, float4 b) {
    bf16x8 r;
    r[0] = (short)f2bf(a.x); r[1] = (short)f2bf(a.y);
    r[2] = (short)f2bf(a.z); r[3] = (short)f2bf(a.w);
    r[4] = (short)f2bf(b.x); r[5] = (short)f2bf(b.y);
    r[6] = (short)f2bf(b.z); r[7] = (short)f2bf(b.w);
    return r;
}

// ------ prep: wsum (block 0) + W -> fragment-contiguous bf16 WB (blocks 1..12)
//        + degree histogram (blocks 13..)
// WB layout: 24 groups (0..3 = W_ni cols 0..63; 4..19 = W_ns cols 0..255;
//            20..23 = W_nj cols 0..63). Per group: 4 K-chunks x 64 lanes x 8
//            bf16, where lane l holds W[k = c*32 + (l>>4)*8 + j][col = g16 + (l&15)].
//            One GEMM B-load = 1 KB fully coalesced.
__global__ void prep_hist(const float* __restrict__ W_fij,
                          const float* __restrict__ W_ni,
                          const float* __restrict__ W_ns,
                          const float* __restrict__ W_nj,
                          const int* __restrict__ dst,
                          float* __restrict__ wsum, unsigned short* __restrict__ WT,
                          int* __restrict__ cnt, int E) {
    int b = blockIdx.x;
    if (b == 0) {
        int k = threadIdx.x;
        if (k < 64) {
            float s = 0.f;
#pragma unroll
            for (int c = 0; c < 16; ++c) s += W_fij[c * 64 + k];
            wsum[k] = s;
        }
        return;
    }
    if (b <= 12) {
        int base = (b - 1) * 4096 + threadIdx.x;
#pragma unroll
        for (int i = 0; i < 16; ++i) {
            int idx = base + i * 256;
            int g   = idx >> 11;          // group (24)
            int rem = idx & 2047;
            int c   = rem >> 9;           // K-chunk (4)
            int l   = (rem >> 3) & 63;    // lane
            int j   = rem & 7;            // element within fragment
            int nl  = l & 15;
            int k   = c * 32 + (l >> 4) * 8 + j;
            unsigned short v;
            if (g < 4)       v = f2bf(W_ni[k * 64  + g * 16 + nl]);
            else if (g < 20) v = f2bf(W_ns[k * 256 + (g - 4) * 16 + nl]);
            else             v = f2bf(W_nj[k * 64  + (g - 20) * 16 + nl]);
            WT[idx] = v;
        }
        return;
    }
    int i = (b - 13) * 256 + threadIdx.x;
    if (i < E) atomicAdd(&cnt[dst[i]], 1);
}

// ------- scan_all: full exclusive scan of cnt -> row_ptr, one dispatch ------
__global__ __launch_bounds__(256) void scan_all(const int* __restrict__ cnt,
                                                int* __restrict__ row_ptr,
                                                int* __restrict__ partials,
                                                int* __restrict__ flags,
                                                int n, int E, int nb) {
    __shared__ int sums[256];
    __shared__ int s_base;
    int tid = threadIdx.x, b = blockIdx.x;
    int base = b * 1024;
    int v[4]; int tsum = 0;
#pragma unroll
    for (int j = 0; j < 4; ++j) {
        int idx = base + tid * 4 + j;
        v[j] = (idx < n) ? cnt[idx] : 0;
        tsum += v[j];
    }
    sums[tid] = tsum;
    __syncthreads();
    for (int off = 1; off < 256; off <<= 1) {
        int x = (tid >= off) ? sums[tid - off] : 0;
        __syncthreads();
        sums[tid] += x;
        __syncthreads();
    }
    if (tid == 255) {
        __hip_atomic_store(&partials[b], sums[255], __ATOMIC_RELAXED, __HIP_MEMORY_SCOPE_AGENT);
        __hip_atomic_store(&flags[b], 1, __ATOMIC_RELEASE, __HIP_MEMORY_SCOPE_AGENT);
    }
    if (tid < 64) {
        int val = 0;
        if (tid < nb) {
            while (__hip_atomic_load(&flags[tid], __ATOMIC_ACQUIRE, __HIP_MEMORY_SCOPE_AGENT) == 0) {
                __builtin_amdgcn_s_sleep(1);
            }
            val = __hip_atomic_load(&partials[tid], __ATOMIC_RELAXED, __HIP_MEMORY_SCOPE_AGENT);
        }
#pragma unroll
        for (int o = 1; o < 64; o <<= 1) {
            int x = __shfl_up(val, o);
            if (tid >= o) val += x;
        }
        int off = (b > 0) ? __shfl(val, b - 1) : 0;
        if (tid == 0) s_base = off;
    }
    __syncthreads();
    int run = s_base + sums[tid] - tsum;   // global exclusive prefix
#pragma unroll
    for (int j = 0; j < 4; ++j) {
        int idx = base + tid * 4 + j;
        if (idx < n) row_ptr[idx] = run;
        run += v[j];
    }
    if (b == nb - 1 && tid == 0) row_ptr[n] = E;
}

// ---- GEMM tile: 64 rows of A x (NG*16) output cols, A staged in LDS once ---
// LDS: 64 x 128 bf16, stored in 16B granules, byte-offset XOR-swizzled with
// (row&7)<<4 so per-lane fragment ds_read_b128 is bank-uniform.
template<int NG, int G0>
__device__ __forceinline__ void gemm_tile(
    const float* __restrict__ A, int rowBase, int M,
    const unsigned short* __restrict__ WB, const float* __restrict__ b_ns,
    unsigned short* __restrict__ f_ni, unsigned short* __restrict__ h_src,
    unsigned short* __restrict__ f_nj, unsigned short* As)
{
    const int t = threadIdx.x;
    const float4* A4 = reinterpret_cast<const float4*>(A);
    // ---- stage A tile (coalesced: 2 loads @ 32B stride cover 2KB/instr-pair)
#pragma unroll
    for (int j = 0; j < 4; ++j) {
        int gi = j * 256 + t;            // granule index (8 floats)
        int r  = gi >> 4;                // tile row (0..63)
        int gr = rowBase + r; if (gr >= M) gr = M - 1;   // clamp, stores guarded
        int fi = (gi & 15) * 2;          // float4 index within row
        float4 a0 = A4[(size_t)gr * 32 + fi];
        float4 a1 = A4[(size_t)gr * 32 + fi + 1];
        int byteoff = (gi * 16) ^ ((r & 7) << 4);
        *reinterpret_cast<bf16x8*>(reinterpret_cast<char*>(As) + byteoff) = cvt8(a0, a1);
    }
    __syncthreads();

    const int lane = t & 63, w = t >> 6;
    const int rw = rowBase + w * 16;
    if (rw >= M) return;                 // tail wave, nothing to compute
    const int m = lane & 15, q = lane >> 4;
    const int tr = w * 16 + m;

    f32x4 acc[NG] = {};
    const char* Asb = reinterpret_cast<const char*>(As);
#pragma unroll
    for (int c = 0; c < 4; ++c) {
        int gi  = tr * 16 + c * 4 + q;
        int off = (gi * 16) ^ ((tr & 7) << 4);
        bf16x8 af = *reinterpret_cast<const bf16x8*>(Asb + off);
#pragma unroll
        for (int g = 0; g < NG; ++g) {
            bf16x8 bf = *reinterpret_cast<const bf16x8*>(
                WB + (size_t)(((G0 + g) * 4 + c) * 64 + lane) * 8);
            acc[g] = __builtin_amdgcn_mfma_f32_16x16x32_bf16(af, bf, acc[g], 0, 0, 0);
        }
    }

#pragma unroll
    for (int g = 0; g < NG; ++g) {
        const int ga = G0 + g;
        unsigned short* C; int N, colBase; const float* bias = nullptr;
        if (ga < 4)       { C = f_ni;  N = 64;  colBase = ga * 16; }
        else if (ga < 20) { C = h_src; N = 256; colBase = (ga - 4) * 16; bias = b_ns; }
        else              { C = f_nj;  N = 64;  colBase = (ga - 20) * 16; }
        int col = colBase + m;
        float bv = bias ? bias[col] : 0.f;
#pragma unroll
        for (int rr = 0; rr < 4; ++rr) {
            int orow = rw + q * 4 + rr;
            if (orow < M) C[(size_t)orow * N + col] = f2bf(acc[g][rr] + bv);
        }
    }
}

// ---------------- mega: gemm + scatter, STRIPED roles (1:2 per 3) -----------
__global__ __launch_bounds__(256) void mega(
    const float* __restrict__ nfeats, const float* __restrict__ dst_feats,
    const unsigned short* __restrict__ WT, const float* __restrict__ b_ns,
    const int* __restrict__ src, const int* __restrict__ dst,
    const float* __restrict__ reward, const int* __restrict__ row_ptr,
    int* __restrict__ cnt,
    unsigned short* __restrict__ f_ni, unsigned short* __restrict__ h_src,
    unsigned short* __restrict__ f_nj, int2* __restrict__ sr_s,
    int Ns, int Nd, int E, int nBlkNf, int nBlkDj, int nScatter)
{
    __shared__ __align__(16) unsigned short As[64 * 128];
    const int g = blockIdx.x / 3, r = blockIdx.x % 3;
    if (r == 0) {                               // ---- GEMM role ----
        if (g < nBlkNf) {
            // nfeats tile: f_ni (64 cols) + h_src (256 cols), A read ONCE
            gemm_tile<20, 0>(nfeats, g * 64, Ns, WT, b_ns, f_ni, h_src, f_nj, As);
        } else if (g < nBlkNf + nBlkDj) {
            gemm_tile<4, 20>(dst_feats, (g - nBlkNf) * 64, Nd, WT, b_ns, f_ni, h_src, f_nj, As);
        }
        return;
    }
    // ---- scatter role ----
    const int sb = g * 2 + (r - 1);
    if (sb >= nScatter) return;
    int i = sb * 256 + threadIdx.x;
    if (i >= E) return;
    int d = dst[i];
    int pos = row_ptr[d] + atomicSub(&cnt[d], 1) - 1;
    sr_s[pos] = make_int2(src[i], __float_as_int(reward[i]));
}

// ------- fused logits + softmax + aggregation: SINGLE online pass -----------
// Unstabilized softmax commutes with the weighted sum: out = (sum ev*h)/den.
// Per quad of edges: 4 subgroups (16 lanes) compute 4 logits/evs in parallel,
// then each ev/sn is broadcast by shuffle and the full wave gathers+accumulates
// that edge's h_src row. No LDS, no MAXD cap, no second edge traversal.
__global__ __launch_bounds__(256) void fused_agg(
    const unsigned short* __restrict__ f_ni, const unsigned short* __restrict__ f_nj,
    const unsigned short* __restrict__ h_src, const int2* __restrict__ sr_s,
    const int* __restrict__ row_ptr,
    const float* __restrict__ wsum, const float* __restrict__ b_e,
    const float* __restrict__ attn, float* __restrict__ out, int Nd)
{
    const int wv = threadIdx.x >> 6, lane = threadIdx.x & 63;
    const int d = blockIdx.x * 4 + wv;
    if (d >= Nd) return;
    const int l = lane & 15, sub = lane >> 4;
    const int beg = row_ptr[d];
    const int end = row_ptr[d + 1];
    const int hsel = (lane >> 4) << 2;      // src lane-pos holding my head's ev/den

    ushort4 uj = *reinterpret_cast<const ushort4*>(f_nj + (size_t)d * HE + 4 * l);
    float4 fnj = { bf2f(uj.x), bf2f(uj.y), bf2f(uj.z), bf2f(uj.w) };
    float4 ws = *reinterpret_cast<const float4*>(wsum + 4 * l);
    float4 be = *reinterpret_cast<const float4*>(b_e + 4 * l);
    float4 at = *reinterpret_cast<const float4*>(attn + 4 * l);

    float den = 0.f;
    float a0 = 0.f, a1 = 0.f, a2 = 0.f, a3 = 0.f;

    const int deg = end - beg;
    const int nfull = deg & ~3;

    // ---- main loop: full quads, no guards ----
    for (int base = beg; base < beg + nfull; base += 4) {
        int2 sr = sr_s[base + sub];
        int sn = sr.x;
        float r = __int_as_float(sr.y);
        ushort4 ui = *reinterpret_cast<const ushort4*>(f_ni + (size_t)sn * HE + 4 * l);
        float t, v;
        v = bf2f(ui.x) + fnj.x + r * ws.x + be.x; v = (v >= 0.f) ? v : LEAKY * v; t  = v * at.x;
        v = bf2f(ui.y) + fnj.y + r * ws.y + be.y; v = (v >= 0.f) ? v : LEAKY * v; t += v * at.y;
        v = bf2f(ui.z) + fnj.z + r * ws.z + be.z; v = (v >= 0.f) ? v : LEAKY * v; t += v * at.z;
        v = bf2f(ui.w) + fnj.w + r * ws.w + be.w; v = (v >= 0.f) ? v : LEAKY * v; t += v * at.w;
        t += __shfl_xor(t, 1);
        t += __shfl_xor(t, 2);              // lanes 4h..4h+3 of subgroup: head h logit
        float ev = __expf(t);
        den += ev;
#pragma unroll
        for (int e = 0; e < 4; ++e) {
            float w  = __shfl(ev, e * 16 + hsel);
            int   sa = __shfl(sn, e * 16);
            ushort4 u = *reinterpret_cast<const ushort4*>(h_src + (size_t)sa * HN + lane * 4);
            a0 = fmaf(w, bf2f(u.x), a0);
            a1 = fmaf(w, bf2f(u.y), a1);
            a2 = fmaf(w, bf2f(u.z), a2);
            a3 = fmaf(w, bf2f(u.w), a3);
        }
    }

    // ---- tail: remaining 0..3 edges ----
    const int rem = deg & 3;
    if (rem) {
        int base = beg + nfull;
        int slot = base + sub;
        float ev = 0.f; int sn = 0;
        if (sub < rem) {
            int2 sr = sr_s[slot];
            sn = sr.x;
            float r = __int_as_float(sr.y);
            ushort4 ui = *reinterpret_cast<const ushort4*>(f_ni + (size_t)sn * HE + 4 * l);
            float t, v;
            v = bf2f(ui.x) + fnj.x + r * ws.x + be.x; v = (v >= 0.f) ? v : LEAKY * v; t  = v * at.x;
            v = bf2f(ui.y) + fnj.y + r * ws.y + be.y; v = (v >= 0.f) ? v : LEAKY * v; t += v * at.y;
            v = bf2f(ui.z) + fnj.z + r * ws.z + be.z; v = (v >= 0.f) ? v : LEAKY * v; t += v * at.z;
            v = bf2f(ui.w) + fnj.w + r * ws.w + be.w; v = (v >= 0.f) ? v : LEAKY * v; t += v * at.w;
            t += __shfl_xor(t, 1);
            t += __shfl_xor(t, 2);
            ev = __expf(t);
            den += ev;
        }
        for (int e = 0; e < rem; ++e) {
            float w  = __shfl(ev, e * 16 + hsel);
            int   sa = __shfl(sn, e * 16);
            ushort4 u = *reinterpret_cast<const ushort4*>(h_src + (size_t)sa * HN + lane * 4);
            a0 = fmaf(w, bf2f(u.x), a0);
            a1 = fmaf(w, bf2f(u.y), a1);
            a2 = fmaf(w, bf2f(u.z), a2);
            a3 = fmaf(w, bf2f(u.w), a3);
        }
    }

    // per-head denominator: den currently holds this lane's subgroup partial
    // for head (l>>2)&3; reduce across subgroups, then pick my head's total.
    den += __shfl_xor(den, 16);
    den += __shfl_xor(den, 32);
    float dh = __shfl(den, hsel);
    float invh = (dh > 0.f) ? 1.f / dh : 0.f;
    a0 *= invh; a1 *= invh; a2 *= invh; a3 *= invh;

    // head mean: reduce across subgroups (lane l holds head l>>4, col (l&15)*4)
    a0 += __shfl_xor(a0, 16); a0 += __shfl_xor(a0, 32);
    a1 += __shfl_xor(a1, 16); a1 += __shfl_xor(a1, 32);
    a2 += __shfl_xor(a2, 16); a2 += __shfl_xor(a2, 32);
    a3 += __shfl_xor(a3, 16); a3 += __shfl_xor(a3, 32);
    if (lane < 16) {
        float4 o = { fmaxf(a0 * 0.25f, 0.f), fmaxf(a1 * 0.25f, 0.f),
                     fmaxf(a2 * 0.25f, 0.f), fmaxf(a3 * 0.25f, 0.f) };
        *reinterpret_cast<float4*>(out + (size_t)d * OUT_NODE + lane * 4) = o;
    }
}

static inline char* align256(char* p) {
    return (char*)(((uintptr_t)p + 255) & ~(uintptr_t)255);
}

extern "C" void kernel_launch(void* const* d_in, const int* in_sizes, int n_in,
                              void* d_out, int out_size, void* d_ws, size_t ws_size,
                              hipStream_t stream) {
    const float* nfeats    = (const float*)d_in[0];
    const float* dst_feats = (const float*)d_in[1];
    const float* reward    = (const float*)d_in[2];
    const int*   src       = (const int*)d_in[3];
    const int*   dst       = (const int*)d_in[4];
    const float* W_ns      = (const float*)d_in[5];
    const float* b_ns      = (const float*)d_in[6];
    const float* W_ni      = (const float*)d_in[7];
    const float* W_nj      = (const float*)d_in[8];
    const float* W_fij     = (const float*)d_in[9];
    const float* attn      = (const float*)d_in[10];
    const float* b_e       = (const float*)d_in[11];
    float* out = (float*)d_out;

    const int Ns = in_sizes[0] / IN_NODE;
    const int Nd = in_sizes[1] / IN_NODE;
    const int E  = in_sizes[2];

    char* ws = (char*)d_ws;
    unsigned short* f_ni  = (unsigned short*)ws; ws = align256(ws + (size_t)Ns * HE * 2);
    unsigned short* f_nj  = (unsigned short*)ws; ws = align256(ws + (size_t)Nd * HE * 2);
    unsigned short* h_src = (unsigned short*)ws; ws = align256(ws + (size_t)Ns * HN * 2);
    unsigned short* WT    = (unsigned short*)ws; ws = align256(ws + 49152 * 2);
    float* wsum    = (float*)ws; ws = align256(ws + HE * 4);
    int*   cnt     = (int*)ws;   // cnt + flags zeroed by one memset
    int*   flags   = cnt + Nd;   ws = align256(ws + (size_t)(Nd + 64) * 4);
    int*   row_ptr = (int*)ws;   ws = align256(ws + (size_t)(Nd + 1) * 4);
    int*   partials= (int*)ws;   ws = align256(ws + 256 * 4);
    int2*  sr_s    = (int2*)ws;  ws = align256(ws + (size_t)E * 8);

    hipMemsetAsync(cnt, 0, (size_t)(Nd + 64) * 4, stream);

    prep_hist<<<13 + (E + 255) / 256, 256, 0, stream>>>(
        W_fij, W_ni, W_ns, W_nj, dst, wsum, WT, cnt, E);

    int nb = (Nd + 1023) / 1024;
    scan_all<<<nb, 256, 0, stream>>>(cnt, row_ptr, partials, flags, Nd, E, nb);

    int nBlkNf = (Ns + 63) / 64;
    int nBlkDj = (Nd + 63) / 64;
    int nG = nBlkNf + nBlkDj;
    int nScatter = (E + 255) / 256;
    int nGroups = (nG > (nScatter + 1) / 2) ? nG : (nScatter + 1) / 2;
    mega<<<nGroups * 3, 256, 0, stream>>>(
        nfeats, dst_feats, WT, b_ns, src, dst, reward, row_ptr, cnt,
        f_ni, h_src, f_nj, sr_s, Ns, Nd, E, nBlkNf, nBlkDj, nScatter);

    fused_agg<<<(Nd + 3) / 4, 256, 0, stream>>>(
        f_ni, f_nj, h_src, sr_s, row_ptr, wsum, b_e, attn, out, Nd);
}

// Round 3
// 273.024 us; speedup vs baseline: 1.1554x; 1.0185x over previous
//
#include <hip/hip_runtime.h>

#define IN_NODE 128
#define OUT_NODE 64
#define NHEAD 4
#define HN 256                 // NHEAD * OUT_NODE
#define HE 64                  // NHEAD * OUT_EDGE
#define LEAKY 0.01f

typedef __attribute__((ext_vector_type(8))) short bf16x8;
typedef __attribute__((ext_vector_type(4))) float f32x4;

__device__ __forceinline__ float bf2f(unsigned short u) {
    union { unsigned u; float f; } v; v.u = ((unsigned)u) << 16; return v.f;
}
__device__ __forceinline__ unsigned short f2bf(float x) {
    union { float f; unsigned u; } v; v.f = x;
    unsigned r = v.u + 0x7FFF + ((v.u >> 16) & 1);   // RNE
    return (unsigned short)(r >> 16);
}
__device__ __forceinline__ bf16x8 cvt8(float4 a, float4 b) {
    bf16x8 r;
    r[0] = (short)f2bf(a.x); r[1] = (short)f2bf(a.y);
    r[2] = (short)f2bf(a.z); r[3] = (short)f2bf(a.w);
    r[4] = (short)f2bf(b.x); r[5] = (short)f2bf(b.y);
    r[6] = (short)f2bf(b.z); r[7] = (short)f2bf(b.w);
    return r;
}

// ------ prep: wsum (block 0) + W -> fragment-contiguous bf16 WB (blocks 1..12)
//        + degree histogram (blocks 13..)
__global__ void prep_hist(const float* __restrict__ W_fij,
                          const float* __restrict__ W_ni,
                          const float* __restrict__ W_ns,
                          const float* __restrict__ W_nj,
                          const int* __restrict__ dst,
                          float* __restrict__ wsum, unsigned short* __restrict__ WT,
                          int* __restrict__ cnt, int E) {
    int b = blockIdx.x;
    if (b == 0) {
        int k = threadIdx.x;
        if (k < 64) {
            float s = 0.f;
#pragma unroll
            for (int c = 0; c < 16; ++c) s += W_fij[c * 64 + k];
            wsum[k] = s;
        }
        return;
    }
    if (b <= 12) {
        int base = (b - 1) * 4096 + threadIdx.x;
#pragma unroll
        for (int i = 0; i < 16; ++i) {
            int idx = base + i * 256;
            int g   = idx >> 11;          // group (24)
            int rem = idx & 2047;
            int c   = rem >> 9;           // K-chunk (4)
            int l   = (rem >> 3) & 63;    // lane
            int j   = rem & 7;            // element within fragment
            int nl  = l & 15;
            int k   = c * 32 + (l >> 4) * 8 + j;
            unsigned short v;
            if (g < 4)       v = f2bf(W_ni[k * 64  + g * 16 + nl]);
            else if (g < 20) v = f2bf(W_ns[k * 256 + (g - 4) * 16 + nl]);
            else             v = f2bf(W_nj[k * 64  + (g - 20) * 16 + nl]);
            WT[idx] = v;
        }
        return;
    }
    int i = (b - 13) * 256 + threadIdx.x;
    if (i < E) atomicAdd(&cnt[dst[i]], 1);
}

// ------- scan_all: full exclusive scan of cnt -> row_ptr, one dispatch ------
__global__ __launch_bounds__(256) void scan_all(const int* __restrict__ cnt,
                                                int* __restrict__ row_ptr,
                                                int* __restrict__ partials,
                                                int* __restrict__ flags,
                                                int n, int E, int nb) {
    __shared__ int sums[256];
    __shared__ int s_base;
    int tid = threadIdx.x, b = blockIdx.x;
    int base = b * 1024;
    int v[4]; int tsum = 0;
#pragma unroll
    for (int j = 0; j < 4; ++j) {
        int idx = base + tid * 4 + j;
        v[j] = (idx < n) ? cnt[idx] : 0;
        tsum += v[j];
    }
    sums[tid] = tsum;
    __syncthreads();
    for (int off = 1; off < 256; off <<= 1) {
        int x = (tid >= off) ? sums[tid - off] : 0;
        __syncthreads();
        sums[tid] += x;
        __syncthreads();
    }
    if (tid == 255) {
        __hip_atomic_store(&partials[b], sums[255], __ATOMIC_RELAXED, __HIP_MEMORY_SCOPE_AGENT);
        __hip_atomic_store(&flags[b], 1, __ATOMIC_RELEASE, __HIP_MEMORY_SCOPE_AGENT);
    }
    if (tid < 64) {
        int val = 0;
        if (tid < nb) {
            while (__hip_atomic_load(&flags[tid], __ATOMIC_ACQUIRE, __HIP_MEMORY_SCOPE_AGENT) == 0) {
                __builtin_amdgcn_s_sleep(1);
            }
            val = __hip_atomic_load(&partials[tid], __ATOMIC_RELAXED, __HIP_MEMORY_SCOPE_AGENT);
        }
#pragma unroll
        for (int o = 1; o < 64; o <<= 1) {
            int x = __shfl_up(val, o);
            if (tid >= o) val += x;
        }
        int off = (b > 0) ? __shfl(val, b - 1) : 0;
        if (tid == 0) s_base = off;
    }
    __syncthreads();
    int run = s_base + sums[tid] - tsum;   // global exclusive prefix
#pragma unroll
    for (int j = 0; j < 4; ++j) {
        int idx = base + tid * 4 + j;
        if (idx < n) row_ptr[idx] = run;
        run += v[j];
    }
    if (b == nb - 1 && tid == 0) row_ptr[n] = E;
}

// ---- GEMM tile: 64 rows of A x (NG*16) output cols, A staged in LDS once ---
template<int NG, int G0>
__device__ __forceinline__ void gemm_tile(
    const float* __restrict__ A, int rowBase, int M,
    const unsigned short* __restrict__ WB, const float* __restrict__ b_ns,
    unsigned short* __restrict__ f_ni, unsigned short* __restrict__ h_src,
    unsigned short* __restrict__ f_nj, unsigned short* As)
{
    const int t = threadIdx.x;
    const float4* A4 = reinterpret_cast<const float4*>(A);
#pragma unroll
    for (int j = 0; j < 4; ++j) {
        int gi = j * 256 + t;            // granule index (8 floats)
        int r  = gi >> 4;                // tile row (0..63)
        int gr = rowBase + r; if (gr >= M) gr = M - 1;   // clamp, stores guarded
        int fi = (gi & 15) * 2;          // float4 index within row
        float4 a0 = A4[(size_t)gr * 32 + fi];
        float4 a1 = A4[(size_t)gr * 32 + fi + 1];
        int byteoff = (gi * 16) ^ ((r & 7) << 4);
        *reinterpret_cast<bf16x8*>(reinterpret_cast<char*>(As) + byteoff) = cvt8(a0, a1);
    }
    __syncthreads();

    const int lane = t & 63, w = t >> 6;
    const int rw = rowBase + w * 16;
    if (rw >= M) return;                 // tail wave, nothing to compute
    const int m = lane & 15, q = lane >> 4;
    const int tr = w * 16 + m;

    f32x4 acc[NG] = {};
    const char* Asb = reinterpret_cast<const char*>(As);
#pragma unroll
    for (int c = 0; c < 4; ++c) {
        int gi  = tr * 16 + c * 4 + q;
        int off = (gi * 16) ^ ((tr & 7) << 4);
        bf16x8 af = *reinterpret_cast<const bf16x8*>(Asb + off);
#pragma unroll
        for (int g = 0; g < NG; ++g) {
            bf16x8 bf = *reinterpret_cast<const bf16x8*>(
                WB + (size_t)(((G0 + g) * 4 + c) * 64 + lane) * 8);
            acc[g] = __builtin_amdgcn_mfma_f32_16x16x32_bf16(af, bf, acc[g], 0, 0, 0);
        }
    }

#pragma unroll
    for (int g = 0; g < NG; ++g) {
        const int ga = G0 + g;
        unsigned short* C; int N, colBase; const float* bias = nullptr;
        if (ga < 4)       { C = f_ni;  N = 64;  colBase = ga * 16; }
        else if (ga < 20) { C = h_src; N = 256; colBase = (ga - 4) * 16; bias = b_ns; }
        else              { C = f_nj;  N = 64;  colBase = (ga - 20) * 16; }
        int col = colBase + m;
        float bv = bias ? bias[col] : 0.f;
#pragma unroll
        for (int rr = 0; rr < 4; ++rr) {
            int orow = rw + q * 4 + rr;
            if (orow < M) C[(size_t)orow * N + col] = f2bf(acc[g][rr] + bv);
        }
    }
}

// ---------------- mega: gemm + scatter, STRIPED roles (1:2 per 3) -----------
__global__ __launch_bounds__(256) void mega(
    const float* __restrict__ nfeats, const float* __restrict__ dst_feats,
    const unsigned short* __restrict__ WT, const float* __restrict__ b_ns,
    const int* __restrict__ src, const int* __restrict__ dst,
    const float* __restrict__ reward, const int* __restrict__ row_ptr,
    int* __restrict__ cnt,
    unsigned short* __restrict__ f_ni, unsigned short* __restrict__ h_src,
    unsigned short* __restrict__ f_nj, int2* __restrict__ sr_s,
    int Ns, int Nd, int E, int nBlkNf, int nBlkDj, int nScatter)
{
    __shared__ __align__(16) unsigned short As[64 * 128];
    const int g = blockIdx.x / 3, r = blockIdx.x % 3;
    if (r == 0) {                               // ---- GEMM role ----
        if (g < nBlkNf) {
            gemm_tile<20, 0>(nfeats, g * 64, Ns, WT, b_ns, f_ni, h_src, f_nj, As);
        } else if (g < nBlkNf + nBlkDj) {
            gemm_tile<4, 20>(dst_feats, (g - nBlkNf) * 64, Nd, WT, b_ns, f_ni, h_src, f_nj, As);
        }
        return;
    }
    // ---- scatter role ----
    const int sb = g * 2 + (r - 1);
    if (sb >= nScatter) return;
    int i = sb * 256 + threadIdx.x;
    if (i >= E) return;
    int d = dst[i];
    int pos = row_ptr[d] + atomicSub(&cnt[d], 1) - 1;
    sr_s[pos] = make_int2(src[i], __float_as_int(reward[i]));
}

// ------- fused logits + softmax + aggregation: pipelined single pass --------
// Subgroup-owns-edge: each 16-lane subgroup processes one edge per quad, and
// gathers its OWN edge's h_src row as 4x128B quarters (quarter j = head j).
// All gather addresses depend only on sr.x, so loads for quad k+1 are issued
// during quad k's compute (sr prefetched 2 ahead). No load result is consumed
// in its issue iteration -> memory latency fully overlapped.
__global__ __launch_bounds__(256) void fused_agg(
    const unsigned short* __restrict__ f_ni, const unsigned short* __restrict__ f_nj,
    const unsigned short* __restrict__ h_src, const int2* __restrict__ sr_s,
    const int* __restrict__ row_ptr,
    const float* __restrict__ wsum, const float* __restrict__ b_e,
    const float* __restrict__ attn, float* __restrict__ out, int Nd)
{
    const int wv = threadIdx.x >> 6, lane = threadIdx.x & 63;
    const int d = blockIdx.x * 4 + wv;
    if (d >= Nd) return;
    const int l = lane & 15, sub = lane >> 4;

    const int beg = row_ptr[d];
    const int end = row_ptr[d + 1];
    const int deg = end - beg;

    if (deg <= 0) {
        if (lane < 16) {
            float4 z = {0.f, 0.f, 0.f, 0.f};
            *reinterpret_cast<float4*>(out + (size_t)d * OUT_NODE + lane * 4) = z;
        }
        return;
    }

    ushort4 uj = *reinterpret_cast<const ushort4*>(f_nj + (size_t)d * HE + 4 * l);
    float4 ws = *reinterpret_cast<const float4*>(wsum + 4 * l);
    float4 be = *reinterpret_cast<const float4*>(b_e + 4 * l);
    float4 at = *reinterpret_cast<const float4*>(attn + 4 * l);
    float4 bb = { bf2f(uj.x) + be.x, bf2f(uj.y) + be.y,
                  bf2f(uj.z) + be.z, bf2f(uj.w) + be.w };   // f_nj + b_e folded

    const int nq = (deg + 3) >> 2;
    const int last = end - 1;

    float den = 0.f;
    f32x4 ac0 = {}, ac1 = {}, ac2 = {}, ac3 = {};

    // slot for quad q (clamped; invalid subgroups masked via ev=0)
#define LDSR(q) ({ int qq = ((q) < nq) ? (q) : (nq - 1);                 \
                   int slot = beg + qq * 4 + sub;                        \
                   if (slot > last) slot = last;                         \
                   sr_s[slot]; })

    int2 srA = LDSR(0);
    int2 srB = LDSR(1);
    const unsigned short* pA = f_ni + (size_t)srA.x * HE + 4 * l;
    ushort4 uiA = *reinterpret_cast<const ushort4*>(pA);
    const unsigned short* hA = h_src + (size_t)srA.x * HN + 4 * l;
    ushort4 uA0 = *reinterpret_cast<const ushort4*>(hA);
    ushort4 uA1 = *reinterpret_cast<const ushort4*>(hA + 64);
    ushort4 uA2 = *reinterpret_cast<const ushort4*>(hA + 128);
    ushort4 uA3 = *reinterpret_cast<const ushort4*>(hA + 192);

    for (int k = 0; k < nq; ++k) {
        // prefetch slot record two ahead
        int2 srC = LDSR(k + 2);
        // prefetch gathers for quad k+1 (srB arrived >=1 iteration ago)
        const unsigned short* pB = f_ni + (size_t)srB.x * HE + 4 * l;
        ushort4 uiB = *reinterpret_cast<const ushort4*>(pB);
        const unsigned short* hB = h_src + (size_t)srB.x * HN + 4 * l;
        ushort4 uB0 = *reinterpret_cast<const ushort4*>(hB);
        ushort4 uB1 = *reinterpret_cast<const ushort4*>(hB + 64);
        ushort4 uB2 = *reinterpret_cast<const ushort4*>(hB + 128);
        ushort4 uB3 = *reinterpret_cast<const ushort4*>(hB + 192);

        // ---- compute quad k (registers only) ----
        float r = __int_as_float(srA.y);
        float v, t;
        v = bf2f(uiA.x) + fmaf(r, ws.x, bb.x); v = fmaxf(v, LEAKY * v); t  = v * at.x;
        v = bf2f(uiA.y) + fmaf(r, ws.y, bb.y); v = fmaxf(v, LEAKY * v); t = fmaf(v, at.y, t);
        v = bf2f(uiA.z) + fmaf(r, ws.z, bb.z); v = fmaxf(v, LEAKY * v); t = fmaf(v, at.z, t);
        v = bf2f(uiA.w) + fmaf(r, ws.w, bb.w); v = fmaxf(v, LEAKY * v); t = fmaf(v, at.w, t);
        t += __shfl_xor(t, 1);
        t += __shfl_xor(t, 2);              // lanes 4h..4h+3 of subgroup: head h logit
        bool valid = (beg + k * 4 + sub) < end;
        float ev = valid ? __expf(t) : 0.f;
        den += ev;                           // lane's head = (l>>2)&3
        // this subgroup's per-head weights
        float w0 = __shfl(ev, (lane & 48));
        float w1 = __shfl(ev, (lane & 48) + 4);
        float w2 = __shfl(ev, (lane & 48) + 8);
        float w3 = __shfl(ev, (lane & 48) + 12);
        ac0[0] = fmaf(w0, bf2f(uA0.x), ac0[0]);
        ac0[1] = fmaf(w0, bf2f(uA0.y), ac0[1]);
        ac0[2] = fmaf(w0, bf2f(uA0.z), ac0[2]);
        ac0[3] = fmaf(w0, bf2f(uA0.w), ac0[3]);
        ac1[0] = fmaf(w1, bf2f(uA1.x), ac1[0]);
        ac1[1] = fmaf(w1, bf2f(uA1.y), ac1[1]);
        ac1[2] = fmaf(w1, bf2f(uA1.z), ac1[2]);
        ac1[3] = fmaf(w1, bf2f(uA1.w), ac1[3]);
        ac2[0] = fmaf(w2, bf2f(uA2.x), ac2[0]);
        ac2[1] = fmaf(w2, bf2f(uA2.y), ac2[1]);
        ac2[2] = fmaf(w2, bf2f(uA2.z), ac2[2]);
        ac2[3] = fmaf(w2, bf2f(uA2.w), ac2[3]);
        ac3[0] = fmaf(w3, bf2f(uA3.x), ac3[0]);
        ac3[1] = fmaf(w3, bf2f(uA3.y), ac3[1]);
        ac3[2] = fmaf(w3, bf2f(uA3.z), ac3[2]);
        ac3[3] = fmaf(w3, bf2f(uA3.w), ac3[3]);

        // rotate pipeline registers
        srA = srB; srB = srC;
        uiA = uiB;
        uA0 = uB0; uA1 = uB1; uA2 = uB2; uA3 = uB3;
    }
#undef LDSR

    // per-head denominators (lane accumulated head (l>>2)&3 of its subgroup)
    den += __shfl_xor(den, 16);
    den += __shfl_xor(den, 32);
    float d0 = __shfl(den, 0), d1 = __shfl(den, 4);
    float d2 = __shfl(den, 8), d3 = __shfl(den, 12);
    float i0 = (d0 > 0.f) ? 0.25f / d0 : 0.f;
    float i1 = (d1 > 0.f) ? 0.25f / d1 : 0.f;
    float i2 = (d2 > 0.f) ? 0.25f / d2 : 0.f;
    float i3 = (d3 > 0.f) ? 0.25f / d3 : 0.f;

    // head-mean combine (per lane: col (l&15)*4+c), then reduce over subgroups
    float o0 = fmaf(ac3[0], i3, fmaf(ac2[0], i2, fmaf(ac1[0], i1, ac0[0] * i0)));
    float o1 = fmaf(ac3[1], i3, fmaf(ac2[1], i2, fmaf(ac1[1], i1, ac0[1] * i0)));
    float o2 = fmaf(ac3[2], i3, fmaf(ac2[2], i2, fmaf(ac1[2], i1, ac0[2] * i0)));
    float o3 = fmaf(ac3[3], i3, fmaf(ac2[3], i2, fmaf(ac1[3], i1, ac0[3] * i0)));
    o0 += __shfl_xor(o0, 16); o0 += __shfl_xor(o0, 32);
    o1 += __shfl_xor(o1, 16); o1 += __shfl_xor(o1, 32);
    o2 += __shfl_xor(o2, 16); o2 += __shfl_xor(o2, 32);
    o3 += __shfl_xor(o3, 16); o3 += __shfl_xor(o3, 32);
    if (lane < 16) {
        float4 o = { fmaxf(o0, 0.f), fmaxf(o1, 0.f),
                     fmaxf(o2, 0.f), fmaxf(o3, 0.f) };
        *reinterpret_cast<float4*>(out + (size_t)d * OUT_NODE + lane * 4) = o;
    }
}

static inline char* align256(char* p) {
    return (char*)(((uintptr_t)p + 255) & ~(uintptr_t)255);
}

extern "C" void kernel_launch(void* const* d_in, const int* in_sizes, int n_in,
                              void* d_out, int out_size, void* d_ws, size_t ws_size,
                              hipStream_t stream) {
    const float* nfeats    = (const float*)d_in[0];
    const float* dst_feats = (const float*)d_in[1];
    const float* reward    = (const float*)d_in[2];
    const int*   src       = (const int*)d_in[3];
    const int*   dst       = (const int*)d_in[4];
    const float* W_ns      = (const float*)d_in[5];
    const float* b_ns      = (const float*)d_in[6];
    const float* W_ni      = (const float*)d_in[7];
    const float* W_nj      = (const float*)d_in[8];
    const float* W_fij     = (const float*)d_in[9];
    const float* attn      = (const float*)d_in[10];
    const float* b_e       = (const float*)d_in[11];
    float* out = (float*)d_out;

    const int Ns = in_sizes[0] / IN_NODE;
    const int Nd = in_sizes[1] / IN_NODE;
    const int E  = in_sizes[2];

    char* ws = (char*)d_ws;
    unsigned short* f_ni  = (unsigned short*)ws; ws = align256(ws + (size_t)Ns * HE * 2);
    unsigned short* f_nj  = (unsigned short*)ws; ws = align256(ws + (size_t)Nd * HE * 2);
    unsigned short* h_src = (unsigned short*)ws; ws = align256(ws + (size_t)Ns * HN * 2);
    unsigned short* WT    = (unsigned short*)ws; ws = align256(ws + 49152 * 2);
    float* wsum    = (float*)ws; ws = align256(ws + HE * 4);
    int*   cnt     = (int*)ws;   // cnt + flags zeroed by one memset
    int*   flags   = cnt + Nd;   ws = align256(ws + (size_t)(Nd + 64) * 4);
    int*   row_ptr = (int*)ws;   ws = align256(ws + (size_t)(Nd + 1) * 4);
    int*   partials= (int*)ws;   ws = align256(ws + 256 * 4);
    int2*  sr_s    = (int2*)ws;  ws = align256(ws + (size_t)E * 8);

    hipMemsetAsync(cnt, 0, (size_t)(Nd + 64) * 4, stream);

    prep_hist<<<13 + (E + 255) / 256, 256, 0, stream>>>(
        W_fij, W_ni, W_ns, W_nj, dst, wsum, WT, cnt, E);

    int nb = (Nd + 1023) / 1024;
    scan_all<<<nb, 256, 0, stream>>>(cnt, row_ptr, partials, flags, Nd, E, nb);

    int nBlkNf = (Ns + 63) / 64;
    int nBlkDj = (Nd + 63) / 64;
    int nG = nBlkNf + nBlkDj;
    int nScatter = (E + 255) / 256;
    int nGroups = (nG > (nScatter + 1) / 2) ? nG : (nScatter + 1) / 2;
    mega<<<nGroups * 3, 256, 0, stream>>>(
        nfeats, dst_feats, WT, b_ns, src, dst, reward, row_ptr, cnt,
        f_ni, h_src, f_nj, sr_s, Ns, Nd, E, nBlkNf, nBlkDj, nScatter);

    fused_agg<<<(Nd + 3) / 4, 256, 0, stream>>>(
        f_ni, f_nj, h_src, sr_s, row_ptr, wsum, b_e, attn, out, Nd);
}